// Round 1
// baseline (106.971 us; speedup 1.0000x reference)
//
#include <hip/hip_runtime.h>

#define RES 64
#define EPS 1e-6f

// Kernel 1: one block per (b, k) pair. 256 threads, each handles 16 pixels.
// Computes per-channel: msum, F = sum m*(fv*fd*64+loc), B = sum m*(bv*bd*64+loc),
// writes [F0/d, F1/d, B0/d, B1/d, msum] to ws[bk*8 + ...].
__global__ __launch_bounds__(256) void reduce_bk_kernel(
    const float* __restrict__ front_vec,
    const float* __restrict__ front_dis,
    const float* __restrict__ back_vec,
    const float* __restrict__ back_dis,
    const float* __restrict__ ske_mask,
    float* __restrict__ ws)
{
    const int bk = blockIdx.x;          // b*20 + k
    const int b  = bk / 20;
    const int k  = bk - b * 20;
    const int t  = threadIdx.x;

    // front_vec (B,40,64,64) viewed as (B,20,64,64,2): flat offsets identical.
    const size_t base_v = (size_t)b * (40 * 4096) + (size_t)k * 8192;
    const size_t base_d = (size_t)b * (20 * 4096) + (size_t)k * 4096;

    const float4* __restrict__ fv4 = (const float4*)(front_vec + base_v);
    const float4* __restrict__ bv4 = (const float4*)(back_vec  + base_v);
    const float4* __restrict__ fd4 = (const float4*)(front_dis + base_d);
    const float4* __restrict__ bd4 = (const float4*)(back_dis  + base_d);
    const float4* __restrict__ m4  = (const float4*)(ske_mask  + base_d);

    float s_m = 0.f, s_F0 = 0.f, s_F1 = 0.f, s_B0 = 0.f, s_B1 = 0.f;

    #pragma unroll
    for (int it = 0; it < 4; ++it) {
        const int g  = it * 256 + t;    // float4 group index over 4096 pixels
        const int p0 = g * 4;           // first pixel of this group
        const float y  = (float)(p0 >> 6);   // row (loc component 0)
        const float x0 = (float)(p0 & 63);   // col of first pixel (component 1)

        const float4 mv = m4[g];
        const float4 fd = fd4[g];
        const float4 bd = bd4[g];
        const float4 f0 = fv4[g * 2 + 0];   // pixels p0, p0+1 : (v0,v1,v0,v1)
        const float4 f1 = fv4[g * 2 + 1];   // pixels p0+2, p0+3
        const float4 g0 = bv4[g * 2 + 0];
        const float4 g1 = bv4[g * 2 + 1];

        s_m += mv.x + mv.y + mv.z + mv.w;

        // per-element, matching reference order: m * (v*d*64 + loc)
        s_F0 += mv.x * fmaf(f0.x * fd.x, 64.f, y)
              + mv.y * fmaf(f0.z * fd.y, 64.f, y)
              + mv.z * fmaf(f1.x * fd.z, 64.f, y)
              + mv.w * fmaf(f1.z * fd.w, 64.f, y);
        s_F1 += mv.x * fmaf(f0.y * fd.x, 64.f, x0)
              + mv.y * fmaf(f0.w * fd.y, 64.f, x0 + 1.f)
              + mv.z * fmaf(f1.y * fd.z, 64.f, x0 + 2.f)
              + mv.w * fmaf(f1.w * fd.w, 64.f, x0 + 3.f);
        s_B0 += mv.x * fmaf(g0.x * bd.x, 64.f, y)
              + mv.y * fmaf(g0.z * bd.y, 64.f, y)
              + mv.z * fmaf(g1.x * bd.z, 64.f, y)
              + mv.w * fmaf(g1.z * bd.w, 64.f, y);
        s_B1 += mv.x * fmaf(g0.y * bd.x, 64.f, x0)
              + mv.y * fmaf(g0.w * bd.y, 64.f, x0 + 1.f)
              + mv.z * fmaf(g1.y * bd.z, 64.f, x0 + 2.f)
              + mv.w * fmaf(g1.w * bd.w, 64.f, x0 + 3.f);
    }

    // 64-lane wave reduction
    #pragma unroll
    for (int off = 32; off > 0; off >>= 1) {
        s_m  += __shfl_down(s_m,  off);
        s_F0 += __shfl_down(s_F0, off);
        s_F1 += __shfl_down(s_F1, off);
        s_B0 += __shfl_down(s_B0, off);
        s_B1 += __shfl_down(s_B1, off);
    }

    __shared__ float red[4][5];
    const int wave = t >> 6;
    const int lane = t & 63;
    if (lane == 0) {
        red[wave][0] = s_m;
        red[wave][1] = s_F0;
        red[wave][2] = s_F1;
        red[wave][3] = s_B0;
        red[wave][4] = s_B1;
    }
    __syncthreads();
    if (t == 0) {
        float m = 0.f, F0 = 0.f, F1 = 0.f, B0 = 0.f, B1 = 0.f;
        #pragma unroll
        for (int w = 0; w < 4; ++w) {
            m  += red[w][0];
            F0 += red[w][1];
            F1 += red[w][2];
            B0 += red[w][3];
            B1 += red[w][4];
        }
        const float denom = m + EPS;
        float* o = ws + (size_t)bk * 8;
        o[0] = F0 / denom;
        o[1] = F1 / denom;
        o[2] = B0 / denom;
        o[3] = B1 / denom;
        o[4] = m;
    }
}

// Kernel 2: one thread per batch element; assemble 21 keypoints.
__global__ __launch_bounds__(256) void assemble_kernel(
    const float* __restrict__ ws, float* __restrict__ out, int B)
{
    const int b = blockIdx.x * blockDim.x + threadIdx.x;
    if (b >= B) return;

    float F[20][2], Bk[20][2], ms[20];
    #pragma unroll
    for (int k = 0; k < 20; ++k) {
        const float* w = ws + (size_t)(b * 20 + k) * 8;
        F[k][0]  = w[0];
        F[k][1]  = w[1];
        Bk[k][0] = w[2];
        Bk[k][1] = w[3];
        ms[k]    = w[4];
    }

    // root keypoint: average of back votes over finger-base channels 0,4,8,12,16
    float r0 = 0.f, r1 = 0.f;
    #pragma unroll
    for (int i = 0; i < 5; ++i) {
        const int c = 4 * i;
        if (ms[c] != 0.f) { r0 += Bk[c][0]; r1 += Bk[c][1]; }
    }

    float* o = out + (size_t)b * 42;
    o[0] = (r0 / 5.f) * 4.f;
    o[1] = (r1 / 5.f) * 4.f;

    #pragma unroll
    for (int i = 0; i < 5; ++i) {
        const int c = 4 * i;
        float* p = o + 2 * (1 + 4 * i);
        // kp[4i+1] = F[4i+3]          (then *4)
        p[0] = F[c + 3][0] * 4.f;
        p[1] = F[c + 3][1] * 4.f;
        // kp[4i+2] = (F[4i+2]+Bk[4i+3])/2 * 4 = (..)*2
        p[2] = (F[c + 2][0] + Bk[c + 3][0]) * 2.f;
        p[3] = (F[c + 2][1] + Bk[c + 3][1]) * 2.f;
        // kp[4i+3] = (F[4i+1]+Bk[4i+2])/2 * 4
        p[4] = (F[c + 1][0] + Bk[c + 2][0]) * 2.f;
        p[5] = (F[c + 1][1] + Bk[c + 2][1]) * 2.f;
        // kp[4i+4] = (F[4i+0]+Bk[4i+1])/2 * 4
        p[6] = (F[c + 0][0] + Bk[c + 1][0]) * 2.f;
        p[7] = (F[c + 0][1] + Bk[c + 1][1]) * 2.f;
    }
}

extern "C" void kernel_launch(void* const* d_in, const int* in_sizes, int n_in,
                              void* d_out, int out_size, void* d_ws, size_t ws_size,
                              hipStream_t stream) {
    const float* front_vec = (const float*)d_in[0];
    const float* front_dis = (const float*)d_in[1];
    const float* back_vec  = (const float*)d_in[2];
    const float* back_dis  = (const float*)d_in[3];
    const float* ske_mask  = (const float*)d_in[4];
    float* out = (float*)d_out;
    float* ws  = (float*)d_ws;

    const int B = in_sizes[1] / (20 * RES * RES);   // 256
    const int nBK = B * 20;                          // 5120 blocks

    reduce_bk_kernel<<<nBK, 256, 0, stream>>>(
        front_vec, front_dis, back_vec, back_dis, ske_mask, ws);

    assemble_kernel<<<(B + 255) / 256, 256, 0, stream>>>(ws, out, B);
}